// Round 1
// baseline (1197.479 us; speedup 1.0000x reference)
//
#include <hip/hip_runtime.h>

// ChannelAttentionModule (DANet channel attention), fp32.
// x: [B=8, C=512, H*W=N=9216], gamma: scalar.
// S = Y Y^T per batch; A = softmax(rowmin-shifted -S); out = gamma*(A Y) + x.

#define TILE 64
#define KT 32

// ---------------- GEMM1: S[b] = Y[b] * Y[b]^T  (C x C, K = N) ----------------
__global__ __launch_bounds__(256) void gram_kernel(const float* __restrict__ x,
                                                   float* __restrict__ att,
                                                   int C, int N) {
    __shared__ float As[KT][TILE + 4];  // [k][c]  (+4 keeps 16B alignment of rows)
    __shared__ float Bs[KT][TILE + 4];  // [k][d]
    const int b  = blockIdx.z;
    const int c0 = blockIdx.y * TILE;
    const int d0 = blockIdx.x * TILE;
    const float* Y = x + (size_t)b * C * N;
    const int t  = threadIdx.x;
    const int tx = t & 15, ty = t >> 4;

    float acc[4][4] = {};
    for (int k0 = 0; k0 < N; k0 += KT) {
        // Stage 64x32 A-tile and B-tile (both are rows of Y, contiguous in k).
        #pragma unroll
        for (int i = 0; i < 2; i++) {
            const int v   = t + i * 256;   // 512 float4 vectors per tile
            const int row = v >> 3;        // 8 float4 per 32-wide row
            const int kq  = v & 7;
            float4 a = *(const float4*)(Y + (size_t)(c0 + row) * N + k0 + kq * 4);
            As[kq * 4 + 0][row] = a.x; As[kq * 4 + 1][row] = a.y;
            As[kq * 4 + 2][row] = a.z; As[kq * 4 + 3][row] = a.w;
            float4 bb = *(const float4*)(Y + (size_t)(d0 + row) * N + k0 + kq * 4);
            Bs[kq * 4 + 0][row] = bb.x; Bs[kq * 4 + 1][row] = bb.y;
            Bs[kq * 4 + 2][row] = bb.z; Bs[kq * 4 + 3][row] = bb.w;
        }
        __syncthreads();
        #pragma unroll
        for (int kk = 0; kk < KT; kk++) {
            float a[4], bb[4];
            #pragma unroll
            for (int i = 0; i < 4; i++) a[i]  = As[kk][ty * 4 + i];
            #pragma unroll
            for (int j = 0; j < 4; j++) bb[j] = Bs[kk][tx * 4 + j];
            #pragma unroll
            for (int i = 0; i < 4; i++)
                #pragma unroll
                for (int j = 0; j < 4; j++)
                    acc[i][j] += a[i] * bb[j];
        }
        __syncthreads();
    }
    float* S = att + (size_t)b * C * C;
    #pragma unroll
    for (int i = 0; i < 4; i++) {
        const int c = c0 + ty * 4 + i;
        float4 v = make_float4(acc[i][0], acc[i][1], acc[i][2], acc[i][3]);
        *(float4*)(S + (size_t)c * C + d0 + tx * 4) = v;
    }
}

// ---------------- softmax over rows of att (row length C=512), in place -------
// softmax(rowmax - s) == softmax(-s); stable shift uses row min of s.
__global__ __launch_bounds__(256) void softmax_kernel(float* __restrict__ att) {
    const int C = 512;
    float* S = att + (size_t)blockIdx.x * C;
    const int t = threadIdx.x;
    const float v0 = S[t], v1 = S[t + 256];

    float mn = fminf(v0, v1);
    #pragma unroll
    for (int off = 32; off > 0; off >>= 1) mn = fminf(mn, __shfl_xor(mn, off));
    __shared__ float redmin[4];
    const int wid = t >> 6, lane = t & 63;
    if (lane == 0) redmin[wid] = mn;
    __syncthreads();
    mn = fminf(fminf(redmin[0], redmin[1]), fminf(redmin[2], redmin[3]));

    const float e0 = expf(mn - v0), e1 = expf(mn - v1);
    float s = e0 + e1;
    #pragma unroll
    for (int off = 32; off > 0; off >>= 1) s += __shfl_xor(s, off);
    __shared__ float redsum[4];
    if (lane == 0) redsum[wid] = s;
    __syncthreads();
    s = redsum[0] + redsum[1] + redsum[2] + redsum[3];

    const float inv = 1.0f / s;
    S[t] = e0 * inv;
    S[t + 256] = e1 * inv;
}

// ---------------- GEMM2: out = gamma * (A[b] * Y[b]) + x  (C x N, K = C) -----
__global__ __launch_bounds__(256) void feat_kernel(const float* __restrict__ att,
                                                   const float* __restrict__ x,
                                                   const float* __restrict__ gamma,
                                                   float* __restrict__ out,
                                                   int C, int N) {
    __shared__ float As[KT][TILE + 4];  // [k(d)][c]
    __shared__ float Bs[KT][TILE + 4];  // [k(d)][n]
    const int b  = blockIdx.z;
    const int c0 = blockIdx.y * TILE;
    const int n0 = blockIdx.x * TILE;
    const float* A = att + (size_t)b * C * C;
    const float* Y = x + (size_t)b * C * N;
    const int t  = threadIdx.x;
    const int tx = t & 15, ty = t >> 4;

    float acc[4][4] = {};
    for (int k0 = 0; k0 < C; k0 += KT) {
        #pragma unroll
        for (int i = 0; i < 2; i++) {
            const int v = t + i * 256;
            // A tile: 64 rows (c) x 32 cols (k) -> store transposed As[k][c]
            const int row = v >> 3, kq = v & 7;
            float4 a = *(const float4*)(A + (size_t)(c0 + row) * C + k0 + kq * 4);
            As[kq * 4 + 0][row] = a.x; As[kq * 4 + 1][row] = a.y;
            As[kq * 4 + 2][row] = a.z; As[kq * 4 + 3][row] = a.w;
            // B tile: 32 rows (k) x 64 cols (n) -> direct float4 store
            const int brow = v >> 4, nq = v & 15;
            float4 bb = *(const float4*)(Y + (size_t)(k0 + brow) * N + n0 + nq * 4);
            *(float4*)(&Bs[brow][nq * 4]) = bb;
        }
        __syncthreads();
        #pragma unroll
        for (int kk = 0; kk < KT; kk++) {
            float a[4], bb[4];
            #pragma unroll
            for (int i = 0; i < 4; i++) a[i]  = As[kk][ty * 4 + i];
            #pragma unroll
            for (int j = 0; j < 4; j++) bb[j] = Bs[kk][tx * 4 + j];
            #pragma unroll
            for (int i = 0; i < 4; i++)
                #pragma unroll
                for (int j = 0; j < 4; j++)
                    acc[i][j] += a[i] * bb[j];
        }
        __syncthreads();
    }

    const float g = gamma[0];
    float* O = out + (size_t)b * C * N;
    const float* X = x + (size_t)b * C * N;
    #pragma unroll
    for (int i = 0; i < 4; i++) {
        const int c = c0 + ty * 4 + i;
        const size_t base = (size_t)c * N + n0 + tx * 4;
        float4 xv = *(const float4*)(X + base);
        float4 r = make_float4(g * acc[i][0] + xv.x, g * acc[i][1] + xv.y,
                               g * acc[i][2] + xv.z, g * acc[i][3] + xv.w);
        *(float4*)(O + base) = r;
    }
}

extern "C" void kernel_launch(void* const* d_in, const int* in_sizes, int n_in,
                              void* d_out, int out_size, void* d_ws, size_t ws_size,
                              hipStream_t stream) {
    const int B = 8, C = 512, N = 96 * 96;
    const float* x     = (const float*)d_in[0];
    const float* gamma = (const float*)d_in[1];
    float* out = (float*)d_out;
    float* att = (float*)d_ws;  // B*C*C fp32 = 8 MB

    dim3 blk(256);
    dim3 grid1(C / TILE, C / TILE, B);           // 8 x 8 x 8
    gram_kernel<<<grid1, blk, 0, stream>>>(x, att, C, N);

    softmax_kernel<<<dim3(B * C), blk, 0, stream>>>(att);

    dim3 grid2(N / TILE, C / TILE, B);           // 144 x 8 x 8
    feat_kernel<<<grid2, blk, 0, stream>>>(att, x, gamma, out, C, N);
}

// Round 2
// 953.766 us; speedup vs baseline: 1.2555x; 1.2555x over previous
//
#include <hip/hip_runtime.h>

// ChannelAttentionModule (DANet channel attention) via bf16 MFMA.
// x: [B=8, C=512, N=96*96=9216] fp32, gamma scalar.
// S = Y Y^T (bf16 MFMA, fp32 acc) -> softmax(rowmin shift) -> bf16 in place
// -> feat = A Y (bf16 MFMA) -> out = gamma*feat + x.

typedef __attribute__((ext_vector_type(8))) short short8;   // 8 bf16 = 4 VGPR
typedef __attribute__((ext_vector_type(4))) float f32x4;    // MFMA C/D

__device__ inline unsigned short f2bf(float f) {
    unsigned u = __builtin_bit_cast(unsigned, f);
    u += 0x7fffu + ((u >> 16) & 1u);          // round-to-nearest-even
    return (unsigned short)(u >> 16);
}
__device__ inline unsigned pack2(float a, float b) {
    return (unsigned)f2bf(a) | ((unsigned)f2bf(b) << 16);
}

// ------------- GEMM1: S[b] = Y Y^T, 64x128 tile, BK=32, K=N ----------------
__global__ __launch_bounds__(256) void gram_kernel(const float* __restrict__ x,
                                                   float* __restrict__ att,
                                                   int C, int N) {
    __shared__ short As[64 * 32];    // [m(c)][k], bf16 bits
    __shared__ short Bs[128 * 32];   // [n(d)][k], bf16 bits
    const int b  = blockIdx.z;
    const int c0 = blockIdx.y * 64;
    const int d0 = blockIdx.x * 128;
    const float* Y = x + (size_t)b * C * N;
    const int t = threadIdx.x;
    const int w = t >> 6, l = t & 63;
    const int mw = (w >> 1) * 32;    // wave: 32 rows x 64 cols
    const int nw = (w & 1) * 64;
    const int lr = l & 15, lq = l >> 4;   // frag row / k-quad

    f32x4 acc[2][4] = {};
    for (int k0 = 0; k0 < N; k0 += 32) {
        // stage A: 64x32 (512 float4 units), convert fp32->bf16
        #pragma unroll
        for (int i = 0; i < 2; i++) {
            const int u = t + i * 256;
            const int row = u >> 3, kq = u & 7;
            float4 v = *(const float4*)(Y + (size_t)(c0 + row) * N + k0 + kq * 4);
            uint2 p = make_uint2(pack2(v.x, v.y), pack2(v.z, v.w));
            *(uint2*)&As[row * 32 + kq * 4] = p;
        }
        // stage B: 128x32 (1024 float4 units)
        #pragma unroll
        for (int i = 0; i < 4; i++) {
            const int u = t + i * 256;
            const int row = u >> 3, kq = u & 7;
            float4 v = *(const float4*)(Y + (size_t)(d0 + row) * N + k0 + kq * 4);
            uint2 p = make_uint2(pack2(v.x, v.y), pack2(v.z, v.w));
            *(uint2*)&Bs[row * 32 + kq * 4] = p;
        }
        __syncthreads();
        short8 af[2], bf[4];
        #pragma unroll
        for (int i = 0; i < 2; i++)
            af[i] = *(short8*)&As[(mw + i * 16 + lr) * 32 + lq * 8];
        #pragma unroll
        for (int j = 0; j < 4; j++)
            bf[j] = *(short8*)&Bs[(nw + j * 16 + lr) * 32 + lq * 8];
        #pragma unroll
        for (int i = 0; i < 2; i++)
            #pragma unroll
            for (int j = 0; j < 4; j++)
                acc[i][j] = __builtin_amdgcn_mfma_f32_16x16x32_bf16(af[i], bf[j], acc[i][j], 0, 0, 0);
        __syncthreads();
    }
    // C/D layout: col = lane&15, row = (lane>>4)*4 + r
    float* S = att + (size_t)b * C * C;
    #pragma unroll
    for (int i = 0; i < 2; i++)
        #pragma unroll
        for (int j = 0; j < 4; j++)
            #pragma unroll
            for (int r = 0; r < 4; r++) {
                const int row = c0 + mw + i * 16 + lq * 4 + r;
                const int col = d0 + nw + j * 16 + lr;
                S[(size_t)row * C + col] = acc[i][j][r];
            }
}

// ------------- softmax over rows (len 512); emits bf16 in place -------------
// softmax(rowmax - s) == softmax(-s); shift by row min for stability.
__global__ __launch_bounds__(256) void softmax_kernel(float* __restrict__ att) {
    const int C = 512;
    float* S = att + (size_t)blockIdx.x * C;
    const int t = threadIdx.x;
    const float v0 = S[t], v1 = S[t + 256];

    float mn = fminf(v0, v1);
    #pragma unroll
    for (int off = 32; off > 0; off >>= 1) mn = fminf(mn, __shfl_xor(mn, off));
    __shared__ float redmin[4];
    const int wid = t >> 6, lane = t & 63;
    if (lane == 0) redmin[wid] = mn;
    __syncthreads();
    mn = fminf(fminf(redmin[0], redmin[1]), fminf(redmin[2], redmin[3]));

    const float e0 = expf(mn - v0), e1 = expf(mn - v1);
    float s = e0 + e1;
    #pragma unroll
    for (int off = 32; off > 0; off >>= 1) s += __shfl_xor(s, off);
    __shared__ float redsum[4];
    if (lane == 0) redsum[wid] = s;
    __syncthreads();
    s = redsum[0] + redsum[1] + redsum[2] + redsum[3];

    const float inv = 1.0f / s;
    // all reads of this row happened before the last __syncthreads -> safe to
    // overwrite the first 1024 bytes of the row with bf16.
    unsigned short* S16 = (unsigned short*)S;
    S16[t] = f2bf(e0 * inv);
    S16[t + 256] = f2bf(e1 * inv);
}

// ------------- GEMM2: out = gamma*(A Y) + x, 128x128 tile, K=C=512 ----------
__global__ __launch_bounds__(256) void feat_kernel(const float* __restrict__ att,
                                                   const float* __restrict__ x,
                                                   const float* __restrict__ gamma,
                                                   float* __restrict__ out,
                                                   int C, int N) {
    __shared__ short As[128 * 32];   // att tile [m(c)][k(d)] bf16
    __shared__ short Bs[128 * 40];   // Y tile transposed [n][k(d)], pad->40
    const int b  = blockIdx.z;
    const int c0 = blockIdx.y * 128;
    const int n0 = blockIdx.x * 128;
    // bf16 att rows live in the low half of each fp32 row: stride 1024 shorts
    const short* Ab = (const short*)(att + (size_t)b * C * C);
    const float* Y = x + (size_t)b * C * N;
    const int t = threadIdx.x;
    const int w = t >> 6, l = t & 63;
    const int mw = (w >> 1) * 64;
    const int nw = (w & 1) * 64;
    const int lr = l & 15, lq = l >> 4;

    f32x4 acc[4][4] = {};
    for (int k0 = 0; k0 < C; k0 += 32) {
        // stage A (bf16 redy): 128x32 shorts = 512 16B-units
        #pragma unroll
        for (int i = 0; i < 2; i++) {
            const int u = t + i * 256;
            const int row = u >> 2, kq = u & 3;
            uint4 v = *(const uint4*)(Ab + (size_t)(c0 + row) * 1024 + k0 + kq * 8);
            *(uint4*)&As[row * 32 + kq * 8] = v;
        }
        // stage B transposed: read Y[k0+d][n0+n] fp32, write Bs[n][d] bf16
        {
            const int d4 = t & 7;          // 4 consecutive d-rows
            const int n4 = t >> 3;         // 4 consecutive n-cols
            float4 r0 = *(const float4*)(Y + (size_t)(k0 + d4 * 4 + 0) * N + n0 + n4 * 4);
            float4 r1 = *(const float4*)(Y + (size_t)(k0 + d4 * 4 + 1) * N + n0 + n4 * 4);
            float4 r2 = *(const float4*)(Y + (size_t)(k0 + d4 * 4 + 2) * N + n0 + n4 * 4);
            float4 r3 = *(const float4*)(Y + (size_t)(k0 + d4 * 4 + 3) * N + n0 + n4 * 4);
            const float c0f[4] = {r0.x, r1.x, r2.x, r3.x};
            const float c1f[4] = {r0.y, r1.y, r2.y, r3.y};
            const float c2f[4] = {r0.z, r1.z, r2.z, r3.z};
            const float c3f[4] = {r0.w, r1.w, r2.w, r3.w};
            const float* cols[4] = {c0f, c1f, c2f, c3f};
            #pragma unroll
            for (int i = 0; i < 4; i++) {
                uint2 p = make_uint2(pack2(cols[i][0], cols[i][1]),
                                     pack2(cols[i][2], cols[i][3]));
                *(uint2*)&Bs[(n4 * 4 + i) * 40 + d4 * 4] = p;
            }
        }
        __syncthreads();
        short8 af[4], bf[4];
        #pragma unroll
        for (int i = 0; i < 4; i++)
            af[i] = *(short8*)&As[(mw + i * 16 + lr) * 32 + lq * 8];
        #pragma unroll
        for (int j = 0; j < 4; j++)
            bf[j] = *(short8*)&Bs[(nw + j * 16 + lr) * 40 + lq * 8];
        #pragma unroll
        for (int i = 0; i < 4; i++)
            #pragma unroll
            for (int j = 0; j < 4; j++)
                acc[i][j] = __builtin_amdgcn_mfma_f32_16x16x32_bf16(af[i], bf[j], acc[i][j], 0, 0, 0);
        __syncthreads();
    }

    const float g = gamma[0];
    float* O = out + (size_t)b * C * N;
    const float* X = x + (size_t)b * C * N;
    #pragma unroll
    for (int i = 0; i < 4; i++)
        #pragma unroll
        for (int j = 0; j < 4; j++)
            #pragma unroll
            for (int r = 0; r < 4; r++) {
                const int row = c0 + mw + i * 16 + lq * 4 + r;
                const int col = n0 + nw + j * 16 + lr;
                const size_t idx = (size_t)row * N + col;
                O[idx] = g * acc[i][j][r] + X[idx];
            }
}

extern "C" void kernel_launch(void* const* d_in, const int* in_sizes, int n_in,
                              void* d_out, int out_size, void* d_ws, size_t ws_size,
                              hipStream_t stream) {
    const int B = 8, C = 512, N = 96 * 96;
    const float* x     = (const float*)d_in[0];
    const float* gamma = (const float*)d_in[1];
    float* out = (float*)d_out;
    float* att = (float*)d_ws;   // B*C*C fp32 = 8 MB

    dim3 blk(256);
    dim3 grid1(C / 128, C / 64, B);        // 4 x 8 x 8 = 256 blocks
    gram_kernel<<<grid1, blk, 0, stream>>>(x, att, C, N);

    softmax_kernel<<<dim3(B * C), blk, 0, stream>>>(att);

    dim3 grid2(N / 128, C / 128, B);       // 72 x 4 x 8 = 2304 blocks
    feat_kernel<<<grid2, blk, 0, stream>>>(att, x, gamma, out, C, N);
}

// Round 3
// 580.774 us; speedup vs baseline: 2.0619x; 1.6422x over previous
//
#include <hip/hip_runtime.h>

// ChannelAttentionModule (DANet channel attention) via bf16 MFMA.
// x: [B=8, C=512, N=96*96=9216] fp32, gamma scalar.
// gram: split-K=4, 128x128 tiles, BK=64, atomic f32 accumulate into att.
// softmax(rowmin shift) -> bf16 in place -> feat = A Y -> out = gamma*feat + x.

typedef __attribute__((ext_vector_type(8))) short short8;   // 8 bf16 = 4 VGPR
typedef __attribute__((ext_vector_type(4))) float f32x4;    // MFMA C/D

#define GT 128      // gram/feat tile (M=N=128)
#define BK 64       // K-chunk
#define LDA 72      // LDS row stride in shorts (144 B: 2-way bank alias = free)
#define SPLITS 4

__device__ inline unsigned short f2bf(float f) {            // RNE (softmax only)
    unsigned u = __builtin_bit_cast(unsigned, f);
    u += 0x7fffu + ((u >> 16) & 1u);
    return (unsigned short)(u >> 16);
}
// pack two fp32 -> two truncated bf16 in ONE v_perm_b32
__device__ inline unsigned permpack(float a, float b) {
    return __builtin_amdgcn_perm(__builtin_bit_cast(unsigned, b),
                                 __builtin_bit_cast(unsigned, a), 0x07060302u);
}

// ---- GEMM1: att[b] += Y Y^T over this block's K-slice (atomic) -------------
__global__ __launch_bounds__(256, 2) void gram_kernel(const float* __restrict__ x,
                                                      float* __restrict__ att,
                                                      int C, int N) {
    __shared__ short As[GT * LDA];
    __shared__ short Bs[GT * LDA];
    const int bz = blockIdx.z;            // split*8 + batch
    const int batch = bz & 7, split = bz >> 3;
    const int c0 = blockIdx.y * GT;
    const int d0 = blockIdx.x * GT;
    const float* Y = x + (size_t)batch * C * N;
    const int t = threadIdx.x;
    const int w = t >> 6, l = t & 63;
    const int mw = (w >> 1) * 64, nw = (w & 1) * 64;
    const int lr = l & 15, lq = l >> 4;

    f32x4 acc[4][4] = {};
    const int kbeg = split * (N / SPLITS);
    const int kend = kbeg + (N / SPLITS);
    for (int k0 = kbeg; k0 < kend; k0 += BK) {
        // stage A and B tiles: 128 rows x 64 k each, fp32 -> bf16(trunc)
        #pragma unroll
        for (int i = 0; i < 8; i++) {
            const int v = t + i * 256;
            const int row = v >> 4, kq = v & 15;
            float4 a = *(const float4*)(Y + (size_t)(c0 + row) * N + k0 + kq * 4);
            uint2 pa = make_uint2(permpack(a.x, a.y), permpack(a.z, a.w));
            *(uint2*)&As[row * LDA + kq * 4] = pa;
            float4 bv = *(const float4*)(Y + (size_t)(d0 + row) * N + k0 + kq * 4);
            uint2 pb = make_uint2(permpack(bv.x, bv.y), permpack(bv.z, bv.w));
            *(uint2*)&Bs[row * LDA + kq * 4] = pb;
        }
        __syncthreads();
        #pragma unroll
        for (int h = 0; h < 2; h++) {
            short8 af[4], bf[4];
            #pragma unroll
            for (int i = 0; i < 4; i++)
                af[i] = *(short8*)&As[(mw + i * 16 + lr) * LDA + h * 32 + lq * 8];
            #pragma unroll
            for (int j = 0; j < 4; j++)
                bf[j] = *(short8*)&Bs[(nw + j * 16 + lr) * LDA + h * 32 + lq * 8];
            #pragma unroll
            for (int i = 0; i < 4; i++)
                #pragma unroll
                for (int j = 0; j < 4; j++)
                    acc[i][j] = __builtin_amdgcn_mfma_f32_16x16x32_bf16(af[i], bf[j], acc[i][j], 0, 0, 0);
        }
        __syncthreads();
    }
    // C/D layout: col = lane&15, row = (lane>>4)*4 + r
    float* S = att + (size_t)batch * C * C;
    #pragma unroll
    for (int i = 0; i < 4; i++)
        #pragma unroll
        for (int j = 0; j < 4; j++)
            #pragma unroll
            for (int r = 0; r < 4; r++) {
                const int row = c0 + mw + i * 16 + lq * 4 + r;
                const int col = d0 + nw + j * 16 + lr;
                unsafeAtomicAdd(&S[(size_t)row * C + col], acc[i][j][r]);
            }
}

// ---- softmax over rows (len 512); emits bf16 in place ----------------------
__global__ __launch_bounds__(256) void softmax_kernel(float* __restrict__ att) {
    const int C = 512;
    float* S = att + (size_t)blockIdx.x * C;
    const int t = threadIdx.x;
    const float v0 = S[t], v1 = S[t + 256];

    float mn = fminf(v0, v1);
    #pragma unroll
    for (int off = 32; off > 0; off >>= 1) mn = fminf(mn, __shfl_xor(mn, off));
    __shared__ float redmin[4];
    const int wid = t >> 6, lane = t & 63;
    if (lane == 0) redmin[wid] = mn;
    __syncthreads();
    mn = fminf(fminf(redmin[0], redmin[1]), fminf(redmin[2], redmin[3]));

    const float e0 = expf(mn - v0), e1 = expf(mn - v1);
    float s = e0 + e1;
    #pragma unroll
    for (int off = 32; off > 0; off >>= 1) s += __shfl_xor(s, off);
    __shared__ float redsum[4];
    if (lane == 0) redsum[wid] = s;
    __syncthreads();
    s = redsum[0] + redsum[1] + redsum[2] + redsum[3];

    const float inv = 1.0f / s;
    unsigned short* S16 = (unsigned short*)S;
    S16[t] = f2bf(e0 * inv);
    S16[t + 256] = f2bf(e1 * inv);
}

// ---- GEMM2: out = gamma*(A Y) + x, 128x128 tile, BK=64, K=C=512 ------------
__global__ __launch_bounds__(256, 2) void feat_kernel(const float* __restrict__ att,
                                                      const float* __restrict__ x,
                                                      const float* __restrict__ gamma,
                                                      float* __restrict__ out,
                                                      int C, int N) {
    __shared__ short As[GT * LDA];   // att tile [c][d] bf16
    __shared__ short Bs[GT * LDA];   // Y tile transposed [n][d] bf16
    const int b  = blockIdx.z;
    const int c0 = blockIdx.y * GT;
    const int n0 = blockIdx.x * GT;
    // bf16 att rows live in the low half of each fp32 row: stride 1024 shorts
    const short* Ab = (const short*)(att + (size_t)b * C * C);
    const float* Y = x + (size_t)b * C * N;
    const int t = threadIdx.x;
    const int w = t >> 6, l = t & 63;
    const int mw = (w >> 1) * 64, nw = (w & 1) * 64;
    const int lr = l & 15, lq = l >> 4;

    f32x4 acc[4][4] = {};
    for (int k0 = 0; k0 < C; k0 += BK) {
        // stage A (already bf16): 128 rows x 64 shorts = 1024 uint4 units
        #pragma unroll
        for (int i = 0; i < 4; i++) {
            const int v = t + i * 256;
            const int row = v >> 3, q = v & 7;
            uint4 va = *(const uint4*)(Ab + (size_t)(c0 + row) * 1024 + k0 + q * 8);
            *(uint4*)&As[row * LDA + q * 8] = va;
        }
        // stage B transposed: Bs[n][k] = Y[k0+k][n0+n]; 512 4x4 micro-tiles
        #pragma unroll
        for (int i = 0; i < 2; i++) {
            const int v = t + i * 256;
            const int kg = v & 15, ng = v >> 4;   // kg: 16 groups of 4 k-rows, ng: 32 groups of 4 n
            const float* p0 = Y + (size_t)(k0 + kg * 4) * N + n0 + ng * 4;
            float4 r0 = *(const float4*)(p0);
            float4 r1 = *(const float4*)(p0 + N);
            float4 r2 = *(const float4*)(p0 + 2 * (size_t)N);
            float4 r3 = *(const float4*)(p0 + 3 * (size_t)N);
            const float j0[4] = {r0.x, r1.x, r2.x, r3.x};
            const float j1[4] = {r0.y, r1.y, r2.y, r3.y};
            const float j2[4] = {r0.z, r1.z, r2.z, r3.z};
            const float j3[4] = {r0.w, r1.w, r2.w, r3.w};
            const float* cols[4] = {j0, j1, j2, j3};
            #pragma unroll
            for (int j = 0; j < 4; j++) {
                uint2 p = make_uint2(permpack(cols[j][0], cols[j][1]),
                                     permpack(cols[j][2], cols[j][3]));
                *(uint2*)&Bs[(ng * 4 + j) * LDA + kg * 4] = p;
            }
        }
        __syncthreads();
        #pragma unroll
        for (int h = 0; h < 2; h++) {
            short8 af[4], bf[4];
            #pragma unroll
            for (int i = 0; i < 4; i++)
                af[i] = *(short8*)&As[(mw + i * 16 + lr) * LDA + h * 32 + lq * 8];
            #pragma unroll
            for (int j = 0; j < 4; j++)
                bf[j] = *(short8*)&Bs[(nw + j * 16 + lr) * LDA + h * 32 + lq * 8];
            #pragma unroll
            for (int i = 0; i < 4; i++)
                #pragma unroll
                for (int j = 0; j < 4; j++)
                    acc[i][j] = __builtin_amdgcn_mfma_f32_16x16x32_bf16(af[i], bf[j], acc[i][j], 0, 0, 0);
        }
        __syncthreads();
    }

    const float g = gamma[0];
    float* O = out + (size_t)b * C * N;
    const float* X = x + (size_t)b * C * N;
    #pragma unroll
    for (int i = 0; i < 4; i++)
        #pragma unroll
        for (int j = 0; j < 4; j++)
            #pragma unroll
            for (int r = 0; r < 4; r++) {
                const int row = c0 + mw + i * 16 + lq * 4 + r;
                const int col = n0 + nw + j * 16 + lr;
                const size_t idx = (size_t)row * N + col;
                O[idx] = g * acc[i][j][r] + X[idx];
            }
}

extern "C" void kernel_launch(void* const* d_in, const int* in_sizes, int n_in,
                              void* d_out, int out_size, void* d_ws, size_t ws_size,
                              hipStream_t stream) {
    const int B = 8, C = 512, N = 96 * 96;
    const float* x     = (const float*)d_in[0];
    const float* gamma = (const float*)d_in[1];
    float* out = (float*)d_out;
    float* att = (float*)d_ws;   // B*C*C fp32 = 8 MB

    hipMemsetAsync(att, 0, (size_t)B * C * C * sizeof(float), stream);

    dim3 blk(256);
    dim3 grid1(C / GT, C / GT, B * SPLITS);   // 4 x 4 x 32 = 512 blocks
    gram_kernel<<<grid1, blk, 0, stream>>>(x, att, C, N);

    softmax_kernel<<<dim3(B * C), blk, 0, stream>>>(att);

    dim3 grid2(N / GT, C / GT, B);            // 72 x 4 x 8 = 2304 blocks
    feat_kernel<<<grid2, blk, 0, stream>>>(att, x, gamma, out, C, N);
}